// Round 1
// baseline (862.525 us; speedup 1.0000x reference)
//
#include <hip/hip_runtime.h>

#define IN_DIM 23
#define HID 128
#define OUTD 64
#define NGR 64

// ---------------- Kernel A: layer-1 edge scatter (23-dim raw feats) + degree --
// 32 threads per edge (lanes 0..22 active for dims, lane 31 bumps degree).
__global__ __launch_bounds__(256) void k_deg_agg0(
    const int* __restrict__ src, const int* __restrict__ dst,
    const float* __restrict__ feat0, float* __restrict__ agg0,
    float* __restrict__ deg, int n_edges)
{
    unsigned t = blockIdx.x * 256u + threadIdx.x;
    int e = (int)(t >> 5);
    int d = (int)(t & 31u);
    if (e >= n_edges) return;
    int s = src[e], v = dst[e];
    if (d < IN_DIM) atomicAdd(&agg0[v * IN_DIM + d], feat0[s * IN_DIM + d]);
    if (d == 31) atomicAdd(&deg[v], 1.0f);
}

// ---------------- Kernel B: fused node transform ----------------------------
// h_neigh = (agg0+feat)/(deg+1); h1 = relu(h_neigh@W1+b1); m1 = (h1/||h1||)@W2
// One wave per 2 nodes (amortizes W1/W2 LDS reads). Weights staged in LDS.
__global__ __launch_bounds__(256) void k_node(
    const float* __restrict__ feat0, const float* __restrict__ agg0,
    const float* __restrict__ deg, const float* __restrict__ W1,
    const float* __restrict__ b1, const float* __restrict__ W2,
    float* __restrict__ m1, int n_nodes)
{
    __shared__ float sW1[IN_DIM * HID];   // [d][k] row-major
    __shared__ float sb1[HID];
    __shared__ float sW2[HID * OUTD];     // [k][o] row-major
    __shared__ float sh1[4][2][HID];      // per-wave normalized h1 for 2 nodes
    __shared__ float shn[4][2][IN_DIM + 1];

    for (int i = threadIdx.x; i < IN_DIM * HID; i += 256) sW1[i] = W1[i];
    if (threadIdx.x < HID) sb1[threadIdx.x] = b1[threadIdx.x];
    for (int i = threadIdx.x; i < HID * OUTD; i += 256) sW2[i] = W2[i];

    int wave = threadIdx.x >> 6;
    int lane = threadIdx.x & 63;
    int vbase = blockIdx.x * 8 + wave * 2;

    // stage h_neigh for the wave's two nodes (lanes 0..45)
    if (lane < 2 * IN_DIM) {
        int tn = lane / IN_DIM, d = lane % IN_DIM;
        int v = vbase + tn;
        if (v < n_nodes) {
            float inv = 1.0f / (deg[v] + 1.0f);
            shn[wave][tn][d] = (agg0[v * IN_DIM + d] + feat0[v * IN_DIM + d]) * inv;
        }
    }
    __syncthreads();

    // each lane computes h1 dims {2*lane, 2*lane+1} for both nodes
    int k0 = lane * 2;
    float sA0 = sb1[k0], sA1 = sb1[k0 + 1];
    float sB0 = sA0, sB1 = sA1;
#pragma unroll
    for (int d = 0; d < IN_DIM; ++d) {
        float2 w = *(const float2*)&sW1[d * HID + k0];   // stride-2 lanes: 2-way, free
        float a = shn[wave][0][d];                        // broadcast
        float b = shn[wave][1][d];
        sA0 += a * w.x; sA1 += a * w.y;
        sB0 += b * w.x; sB1 += b * w.y;
    }
    sA0 = fmaxf(sA0, 0.f); sA1 = fmaxf(sA1, 0.f);
    sB0 = fmaxf(sB0, 0.f); sB1 = fmaxf(sB1, 0.f);
    float ssqA = sA0 * sA0 + sA1 * sA1;
    float ssqB = sB0 * sB0 + sB1 * sB1;
#pragma unroll
    for (int off = 32; off; off >>= 1) {
        ssqA += __shfl_xor(ssqA, off);
        ssqB += __shfl_xor(ssqB, off);
    }
    float scA = 1.0f / fmaxf(sqrtf(ssqA), 1e-12f);
    float scB = 1.0f / fmaxf(sqrtf(ssqB), 1e-12f);
    sh1[wave][0][k0] = sA0 * scA; sh1[wave][0][k0 + 1] = sA1 * scA;
    sh1[wave][1][k0] = sB0 * scB; sh1[wave][1][k0 + 1] = sB1 * scB;
    __syncthreads();

    // m1[o] = sum_k h1n[k] * W2[k][o]; lane o, one W2 read serves 2 nodes
    float acc0 = 0.f, acc1 = 0.f;
#pragma unroll 8
    for (int k = 0; k < HID; ++k) {
        float w2 = sW2[k * OUTD + lane];      // stride-1 lanes: conflict-free
        acc0 += sh1[wave][0][k] * w2;         // broadcast
        acc1 += sh1[wave][1][k] * w2;
    }
    int v0 = vbase, v1 = vbase + 1;
    if (v0 < n_nodes) m1[v0 * OUTD + lane] = acc0;   // coalesced 256B per wave
    if (v1 < n_nodes) m1[v1 * OUTD + lane] = acc1;
}

// ---------------- Kernel C: layer-2 edge scatter on 64-dim m1 ----------------
// One wave per edge: coalesced gather of m1[src], coalesced atomics to aggm[dst].
__global__ __launch_bounds__(256) void k_scatter2(
    const int* __restrict__ src, const int* __restrict__ dst,
    const float* __restrict__ m1, float* __restrict__ aggm, int n_edges)
{
    unsigned t = blockIdx.x * 256u + threadIdx.x;
    int e = (int)(t >> 6);
    int d = (int)(t & 63u);
    if (e >= n_edges) return;
    int s = src[e], v = dst[e];
    atomicAdd(&aggm[v * OUTD + d], m1[s * OUTD + d]);
}

// ---------------- Kernel D: per-graph sum with LDS privatization -------------
__global__ __launch_bounds__(256) void k_graphsum(
    const float* __restrict__ m1, const float* __restrict__ aggm,
    const float* __restrict__ deg, const int* __restrict__ gids,
    float* __restrict__ gsum, float* __restrict__ gcnt, int n_nodes)
{
    __shared__ float lsum[NGR * OUTD];
    __shared__ float lcnt[NGR];
    for (int i = threadIdx.x; i < NGR * OUTD; i += 256) lsum[i] = 0.f;
    if (threadIdx.x < NGR) lcnt[threadIdx.x] = 0.f;
    __syncthreads();

    int lane = threadIdx.x & 63;
    int w = (int)((blockIdx.x * 256u + threadIdx.x) >> 6);
    int nw = (int)((gridDim.x * 256u) >> 6);
    for (int v = w; v < n_nodes; v += nw) {
        int g = gids[v];
        float inv = 1.0f / (deg[v] + 1.0f);
        float val = (aggm[v * OUTD + lane] + m1[v * OUTD + lane]) * inv;
        atomicAdd(&lsum[g * OUTD + lane], val);
        if (lane == 0) atomicAdd(&lcnt[g], 1.0f);
    }
    __syncthreads();
    for (int i = threadIdx.x; i < NGR * OUTD; i += 256) atomicAdd(&gsum[i], lsum[i]);
    if (threadIdx.x < NGR) atomicAdd(&gcnt[threadIdx.x], lcnt[threadIdx.x]);
}

// ---------------- Kernel E: finalize: mean + b2 ------------------------------
__global__ __launch_bounds__(256) void k_final(
    const float* __restrict__ gsum, const float* __restrict__ gcnt,
    const float* __restrict__ b2, float* __restrict__ out)
{
    int i = blockIdx.x * 256 + threadIdx.x;
    if (i >= NGR * OUTD) return;
    int g = i >> 6, d = i & 63;
    float c = gcnt[g];
    out[i] = (c > 0.f) ? (gsum[i] / c + b2[d]) : 0.f;
}

extern "C" void kernel_launch(void* const* d_in, const int* in_sizes, int n_in,
                              void* d_out, int out_size, void* d_ws, size_t ws_size,
                              hipStream_t stream) {
    const float* feat0 = (const float*)d_in[0];
    const float* W1    = (const float*)d_in[1];
    const float* b1    = (const float*)d_in[2];
    const float* W2    = (const float*)d_in[3];
    const float* b2    = (const float*)d_in[4];
    const int*   src   = (const int*)d_in[5];
    const int*   dst   = (const int*)d_in[6];
    const int*   gids  = (const int*)d_in[7];
    int n_edges = in_sizes[5];
    int n_nodes = in_sizes[7];

    // workspace layout (floats): deg | agg0 | aggm | gsum | gcnt | m1
    float* deg  = (float*)d_ws;
    float* agg0 = deg  + n_nodes;
    float* aggm = agg0 + (size_t)n_nodes * IN_DIM;
    float* gsum = aggm + (size_t)n_nodes * OUTD;
    float* gcnt = gsum + NGR * OUTD;
    float* m1   = gcnt + NGR;

    size_t zero_floats = (size_t)n_nodes * (1 + IN_DIM + OUTD) + NGR * OUTD + NGR;
    hipMemsetAsync(deg, 0, zero_floats * sizeof(float), stream);

    unsigned blkA = (unsigned)(((long long)n_edges * 32 + 255) / 256);
    k_deg_agg0<<<blkA, 256, 0, stream>>>(src, dst, feat0, agg0, deg, n_edges);

    unsigned blkB = (unsigned)((n_nodes + 7) / 8);
    k_node<<<blkB, 256, 0, stream>>>(feat0, agg0, deg, W1, b1, W2, m1, n_nodes);

    unsigned blkC = (unsigned)(((long long)n_edges * 64 + 255) / 256);
    k_scatter2<<<blkC, 256, 0, stream>>>(src, dst, m1, aggm, n_edges);

    k_graphsum<<<512, 256, 0, stream>>>(m1, aggm, deg, gids, gsum, gcnt, n_nodes);

    k_final<<<(NGR * OUTD + 255) / 256, 256, 0, stream>>>(gsum, gcnt, b2, (float*)d_out);
}